// Round 12
// baseline (198.003 us; speedup 1.0000x reference)
//
#include <hip/hip_runtime.h>

// SSA forward, f32 I/O:
//   q = heads(lif(bn(x Wq^T))), k = heads(lif(bn(x Wk^T))), v = heads(bn(x Wv^T))
//   o = 0.125 * q @ (k^T v)   (no softmax -> associativity), out = bn(o Wp^T)
// Q/K GEMMs: 3-term bf16 split (xh*wh + xl*wh + xh*wl) for ~f32 accuracy.
// Row permutation m' = ((b*N+n)*T + t): LIF fused in GEMM epilogue; k/v
// written directly transposed [t,b,c,n] via LDS-transpose epilogue.
// qk GEMM: A staged via global_load_lds (depth-4, counted vmcnt); B read
// DIRECTLY from global into registers (L2-resident weights) -> LDS read
// traffic 12->4 per wave-slot, below the MFMA cycle floor. 5 dispatches.

#define T_ 4
#define B_ 4
#define N_ 1024
#define C_ 512
#define H_ 8
#define M_ (T_*B_*N_)   // 16384

typedef __bf16 bf16x8 __attribute__((ext_vector_type(8)));
typedef float  floatx4 __attribute__((ext_vector_type(4)));

__device__ __forceinline__ float bf2f(unsigned short u) {
  union { unsigned int i; float f; } v; v.i = ((unsigned int)u) << 16; return v.f;
}
__device__ __forceinline__ unsigned short f2bf(float f) {
  unsigned int x = __float_as_uint(f);
  return (unsigned short)((x + 0x7fffu + ((x >> 16) & 1u)) >> 16);  // RNE
}

#define GLOAD16(gaddr, ldsbase) \
  __builtin_amdgcn_global_load_lds((__attribute__((address_space(1))) void*)(gaddr), \
                                   (__attribute__((address_space(3))) void*)(ldsbase), 16, 0, 0)

struct BnParams { const float* p[20]; };
struct PrepArgs {
  const float *x, *qw, *kw, *vw, *pw;
  unsigned short *X2, *Wqk3, *Wvb, *Wpb;
  float *scl, *sft;
  BnParams bp;
};

// One dispatch: blocks [0,8192) x-split, [8192,9216) weights, [9216,9224) bn.
__global__ __launch_bounds__(256) void prep_all(PrepArgs P) {
  const int bid = blockIdx.x;
  if (bid < 8192) {
    const int idx = (bid * 256 + threadIdx.x) * 4;
    const float4 v = *(const float4*)(P.x + idx);
    const int m = idx >> 9, k = idx & 511;
    const int t = m >> 12, b = (m >> 10) & 3, n = m & 1023;
    const int mp = (((b << 10) | n) << 2) | t;
    const size_t base = (size_t)mp * 1024 + k;
    float vv[4] = {v.x, v.y, v.z, v.w};
    unsigned short h[4], l[4];
#pragma unroll
    for (int j = 0; j < 4; ++j) { h[j] = f2bf(vv[j]); l[j] = f2bf(vv[j] - bf2f(h[j])); }
    *(ushort4*)(P.X2 + base) = ushort4{h[0], h[1], h[2], h[3]};
    *(ushort4*)(P.X2 + base + 512) = ushort4{l[0], l[1], l[2], l[3]};
  } else if (bid < 9216) {
    const int z = (bid - 8192) >> 8;
    const int idx = ((((bid - 8192) & 255) * 256) + threadIdx.x) * 4;
    const float* src = (z == 0) ? P.qw : (z == 1) ? P.kw : (z == 2) ? P.vw : P.pw;
    const float4 v = *(const float4*)(src + idx);
    if (z >= 2) {
      unsigned short* dst = (z == 2) ? P.Wvb : P.Wpb;
      *(ushort4*)(dst + idx) = ushort4{f2bf(v.x), f2bf(v.y), f2bf(v.z), f2bf(v.w)};
      return;
    }
    const int row = idx >> 9, k = idx & 511;
    unsigned short* dst = P.Wqk3 + (size_t)(z * 512) * 1536;
    const size_t base = (size_t)row * 1536 + k;
    float vv[4] = {v.x, v.y, v.z, v.w};
    unsigned short h[4], l[4];
#pragma unroll
    for (int j = 0; j < 4; ++j) { h[j] = f2bf(vv[j]); l[j] = f2bf(vv[j] - bf2f(h[j])); }
    ushort4 hi{h[0], h[1], h[2], h[3]};
    *(ushort4*)(dst + base) = hi;
    *(ushort4*)(dst + base + 512) = hi;
    *(ushort4*)(dst + base + 1024) = ushort4{l[0], l[1], l[2], l[3]};
  } else {
    const int o = (bid - 9216) * 256 + threadIdx.x;
    const int grp = o >> 9, ci = o & 511;
    const float s = P.bp.p[grp * 5 + 1][ci] * rsqrtf(P.bp.p[grp * 5 + 4][ci] + 1e-5f);
    P.scl[o] = s;
    P.sft[o] = (P.bp.p[grp * 5 + 0][ci] - P.bp.p[grp * 5 + 3][ci]) * s + P.bp.p[grp * 5 + 2][ci];
  }
}

struct Job2 {
  const unsigned short* A; int lda;
  const unsigned short* w; int ldb;
  int K, ldc, epi;  // epi: 2=qk dual (q->qsb, k->LDS-transpose->ktr)
                    //      3=f32 unpermuted, 4=bf16 LDS-transpose (v->vtr)
  const float* scl; const float* sft;
  float* out32; unsigned short* out16; unsigned short* out16b;
};

// ---------------------------------------------------------------------------
// qk body: 256x256, BK=32, A via LDS (depth-4), B direct-from-global regs.
// ---------------------------------------------------------------------------
__device__ __forceinline__ void qk_body(const Job2& job, int bx,
                                        unsigned short (*AB)[256 * 64]) {
  const int xcd = bx & 7, slot = bx >> 3;
  const int panel = xcd + 8 * (slot >> 2);
  const int m0 = panel * 256;
  const int n0 = (slot & 3) * 256;

  const int tid = threadIdx.x;
  const int wv = tid >> 6, lane = tid & 63;
  const int wm = wv >> 1, wn = wv & 1;
  const int NT = job.K >> 5;   // 48

  // staging (combined A+B 128B rows, unchanged mapping; B half unread)
  const int rloc = lane >> 3;
  const int ulog = (lane & 7) ^ rloc;
  const bool isA = ulog < 4;
  const unsigned short* bq[4];
#pragma unroll
  for (int q = 0; q < 4; ++q) {
    const int row = wv * 32 + q * 8 + rloc;
    bq[q] = isA ? job.A + (size_t)(m0 + row) * job.lda + ulog * 8
                : job.w + (size_t)(n0 + row) * job.ldb + (ulog - 4) * 8;
  }

#define ISSUE(T_, BUF_) do {                                                 \
    const int t_ = (T_);                                                     \
    const int off_ = isA ? ((t_ < 32 ? t_ : t_ - 32) << 5) : (t_ << 5);      \
    _Pragma("unroll")                                                        \
    for (int q = 0; q < 4; ++q)                                              \
      GLOAD16(bq[q] + off_, &AB[BUF_][(wv * 32 + q * 8) * 64]);              \
  } while (0)

  const int r15 = lane & 15;
  const int koff = (lane >> 4) * 8;
  const int apos = (lane >> 4) ^ (lane & 7);
  const int aoff = (wm * 64 + r15) * 64 + apos * 8;

  // B direct-load pointers (8 j-frags per wave column)
  const unsigned short* wb[8];
#pragma unroll
  for (int j = 0; j < 8; ++j)
    wb[j] = job.w + (size_t)(n0 + wn * 128 + j * 16 + r15) * job.ldb + koff;

  bf16x8 A0[4], A1[4], B0[8], B1[8];

#define RD_A(BUF_, AX) do {                                                  \
    const unsigned short* lb_ = &AB[BUF_][0];                                \
    _Pragma("unroll")                                                        \
    for (int i_ = 0; i_ < 4; ++i_) AX[i_] = *(const bf16x8*)(lb_ + aoff + i_ * 1024); \
  } while (0)

#define LOADB(T_, BV) do {                                                   \
    const int kB_ = (T_) << 5;                                               \
    _Pragma("unroll")                                                        \
    for (int j_ = 0; j_ < 8; ++j_) BV[j_] = *(const bf16x8*)(wb[j_] + kB_);  \
  } while (0)

#define MF_LO(AX, BV) do {                                                   \
    __builtin_amdgcn_s_setprio(1);                                           \
    _Pragma("unroll")                                                        \
    for (int j_ = 0; j_ < 4; ++j_)                                           \
    _Pragma("unroll")                                                        \
      for (int i_ = 0; i_ < 4; ++i_)                                         \
        acc[i_][j_] = __builtin_amdgcn_mfma_f32_16x16x32_bf16(AX[i_], BV[j_], acc[i_][j_], 0, 0, 0); \
    __builtin_amdgcn_s_setprio(0);                                           \
  } while (0)

#define MF_HI(AX, BV) do {                                                   \
    __builtin_amdgcn_s_setprio(1);                                           \
    _Pragma("unroll")                                                        \
    for (int i_ = 0; i_ < 4; ++i_)                                           \
    _Pragma("unroll")                                                        \
      for (int j_ = 0; j_ < 4; ++j_)                                         \
        acc[i_][4 + j_] = __builtin_amdgcn_mfma_f32_16x16x32_bf16(AX[i_], BV[4 + j_], acc[i_][4 + j_], 0, 0, 0); \
    __builtin_amdgcn_s_setprio(0);                                           \
  } while (0)

#define MIDBAR(N_) do {                                                      \
    asm volatile("s_waitcnt vmcnt(" #N_ ")" ::: "memory");                   \
    __builtin_amdgcn_s_barrier();                                            \
    __builtin_amdgcn_sched_barrier(0);                                       \
  } while (0)

// slot kt: p0 {LOADB(kt+1)->BY, MF_LO(kt)} | vmcnt32+bar |
//          p1 {ISSUE A(kt+4)->buf kt&3, RD_A(kt+1), MF_HI(kt)}
// vmcnt(32): newer-than-A(kt+1) = [B(kt-1)8+A(kt+2)4] + [B(kt)8+A(kt+3)4] + B(kt+1)8
#define SLOT_I(KT_, BC_, BN_, AX, BX, AY, BY) do {                           \
    LOADB((KT_) + 1, BY); MF_LO(AX, BX);                                     \
    MIDBAR(32);                                                              \
    ISSUE((KT_) + 4, BC_);                                                   \
    RD_A(BN_, AY); MF_HI(AX, BX);                                            \
  } while (0)

  floatx4 acc[4][8];
#pragma unroll
  for (int i = 0; i < 4; ++i)
#pragma unroll
    for (int j = 0; j < 8; ++j) acc[i][j] = floatx4{0.f, 0.f, 0.f, 0.f};

  // prologue: B(0) then A tiles 0..3; newer-than-{B(0),A(0)} = 12
  LOADB(0, B0);
  ISSUE(0, 0); ISSUE(1, 1); ISSUE(2, 2); ISSUE(3, 3);
  asm volatile("s_waitcnt vmcnt(12)" ::: "memory");
  __builtin_amdgcn_s_barrier();
  __builtin_amdgcn_sched_barrier(0);
  RD_A(0, A0);

  const int NG = (NT - 4) >> 2;   // 11 groups, slots 0..NT-5
  for (int g = 0; g < NG; ++g) {
    const int g4 = g << 2;
    SLOT_I(g4 + 0, 0, 1, A0, B0, A1, B1);
    SLOT_I(g4 + 1, 1, 2, A1, B1, A0, B0);
    SLOT_I(g4 + 2, 2, 3, A0, B0, A1, B1);
    SLOT_I(g4 + 3, 3, 0, A1, B1, A0, B0);
  }
  // tail slots NT-4..NT-1 (no A-issues; drain 32 -> 28 -> 24)
  LOADB(NT - 3, B1); MF_LO(A0, B0); MIDBAR(32); RD_A(1, A1); MF_HI(A0, B0);
  LOADB(NT - 2, B0); MF_LO(A1, B1); MIDBAR(28); RD_A(2, A0); MF_HI(A1, B1);
  LOADB(NT - 1, B1); MF_LO(A0, B0); MIDBAR(24); RD_A(3, A1); MF_HI(A0, B0);
  MF_LO(A1, B1); MF_HI(A1, B1);

  // ---- epilogue
  float scl[8], sft[8];
#pragma unroll
  for (int j = 0; j < 8; ++j) {
    const int c = n0 + wn * 128 + j * 16 + r15;
    scl[j] = job.scl[c];
    sft[j] = job.sft[c];
  }
  const int rbase = m0 + wm * 64 + (lane >> 4) * 4;

  if (n0 < 512) {
    // q half: BN -> in-register LIF -> qsb [m'][512]
    const int cb = n0 + wn * 128 + r15;
#pragma unroll
    for (int i = 0; i < 4; ++i) {
      unsigned short spk[4][8];
#pragma unroll
      for (int j = 0; j < 8; ++j) {
        float vme = 0.f;
#pragma unroll
        for (int r = 0; r < 4; ++r) {
          const float y = acc[i][j][r] * scl[j] + sft[j];
          vme += (y - vme) * 0.5f;
          const bool sp = vme >= 1.0f;
          spk[r][j] = sp ? (unsigned short)0x3F80 : (unsigned short)0;
          if (sp) vme = 0.f;
        }
      }
#pragma unroll
      for (int r = 0; r < 4; ++r) {
        unsigned short* prow = job.out16 + (size_t)(rbase + 16 * i + r) * 512 + cb;
#pragma unroll
        for (int j = 0; j < 8; ++j) prow[j * 16] = spk[r][j];
      }
    }
  } else {
    // k half: BN -> LIF -> LDS [4t][256c][64n] (swizzled) -> ktr [t,b,c,n]
    __syncthreads();
    unsigned short* lds = &AB[0][0];
    const int gq = lane >> 4;
#pragma unroll
    for (int i = 0; i < 4; ++i) {
      const int n_loc = wm * 16 + 4 * i + gq;
#pragma unroll
      for (int j = 0; j < 8; ++j) {
        const int c_loc = wn * 128 + j * 16 + r15;
        const int colbase = c_loc * 64 + (n_loc ^ ((c_loc & 7) << 3));
        float vme = 0.f;
#pragma unroll
        for (int r = 0; r < 4; ++r) {
          const float y = acc[i][j][r] * scl[j] + sft[j];
          vme += (y - vme) * 0.5f;
          const bool sp = vme >= 1.0f;
          lds[r * 16384 + colbase] = sp ? (unsigned short)0x3F80 : (unsigned short)0;
          if (sp) vme = 0.f;
        }
      }
    }
    __syncthreads();
    const int b = panel >> 4, n0g = (panel & 15) * 64, cb = n0 - 512;
#pragma unroll
    for (int it = 0; it < 16; ++it) {
      const int rho = wv * 128 + it * 8 + (lane >> 3);
      const int t = rho >> 8, c = rho & 255;
      const int nb = lane & 7;
      const uint4 d = *(const uint4*)&lds[t * 16384 + c * 64 + ((nb ^ (c & 7)) << 3)];
      *(uint4*)(job.out16b + (size_t)((t * 4 + b) * 512 + cb + c) * 1024 + n0g + nb * 8) = d;
    }
  }
}

// ---------------------------------------------------------------------------
// 128x256 body (v/proj): K=512 (NT=16). Depth-4 prefetch. Frozen.
// ---------------------------------------------------------------------------
__device__ __forceinline__ void v_body(const Job2& job, int bx,
                                       unsigned short (*ABS)[384 * 32]) {
  const int xcd = bx & 7, slot = bx >> 3;
  const int panel = xcd + 8 * (slot >> 1);
  const int m0 = panel * 128;
  const int n0 = (slot & 1) * 256;

  const int tid = threadIdx.x;
  const int wv = tid >> 6, lane = tid & 63;
  const int wm = wv >> 2, wn = wv & 3;

  const unsigned short* src[3];
#pragma unroll
  for (int g = 0; g < 3; ++g) {
    const int row = wv * 48 + g * 16 + (lane >> 2);
    const int ulog = (lane & 3) ^ (row & 3);
    src[g] = (row < 128) ? job.A + (size_t)(m0 + row) * job.lda + ulog * 8
                         : job.w + (size_t)(n0 + row - 128) * job.ldb + ulog * 8;
  }

#define ISSUE1(T_, BUF_) do {                                                \
    const int k0_ = (T_) << 5;                                               \
    _Pragma("unroll")                                                        \
    for (int g_ = 0; g_ < 3; ++g_)                                           \
      GLOAD16(src[g_] + k0_, &ABS[BUF_][(wv * 48 + g_ * 16) * 32]);          \
  } while (0)

  const int r15 = lane & 15;
  const int uoff = ((lane >> 4) ^ (r15 & 3)) << 3;
  const int arow0 = (wm * 64 + r15) * 32 + uoff;
  const int brow0 = (128 + wn * 64 + r15) * 32 + uoff;

  bf16x8 AX[4], BX[4], AY[4], BY[4];
#define RD1(BUF_, A_, B_) do {                                               \
    const unsigned short* lb_ = &ABS[BUF_][0];                               \
    _Pragma("unroll")                                                        \
    for (int i_ = 0; i_ < 4; ++i_) A_[i_] = *(const bf16x8*)(lb_ + arow0 + i_ * 512); \
    _Pragma("unroll")                                                        \
    for (int j_ = 0; j_ < 4; ++j_) B_[j_] = *(const bf16x8*)(lb_ + brow0 + j_ * 512); \
  } while (0)

#define MF1(A_, B_) do {                                                     \
    __builtin_amdgcn_s_setprio(1);                                           \
    _Pragma("unroll")                                                        \
    for (int i_ = 0; i_ < 4; ++i_)                                           \
    _Pragma("unroll")                                                        \
      for (int j_ = 0; j_ < 4; ++j_)                                         \
        acc[i_][j_] = __builtin_amdgcn_mfma_f32_16x16x32_bf16(A_[i_], B_[j_], acc[i_][j_], 0, 0, 0); \
    __builtin_amdgcn_s_setprio(0);                                           \
  } while (0)

#define MB1(N_) do {                                                         \
    asm volatile("s_waitcnt vmcnt(" #N_ ")" ::: "memory");                   \
    __builtin_amdgcn_s_barrier();                                            \
    __builtin_amdgcn_sched_barrier(0);                                       \
  } while (0)

  floatx4 acc[4][4];
#pragma unroll
  for (int i = 0; i < 4; ++i)
#pragma unroll
    for (int j = 0; j < 4; ++j) acc[i][j] = floatx4{0.f, 0.f, 0.f, 0.f};

  ISSUE1(0, 0); ISSUE1(1, 1); ISSUE1(2, 2); ISSUE1(3, 3);
  asm volatile("s_waitcnt vmcnt(9)" ::: "memory");
  __builtin_amdgcn_s_barrier();
  __builtin_amdgcn_sched_barrier(0);
  RD1(0, AX, BX);

#pragma unroll 1
  for (int kt = 0; kt < 12; kt += 2) {
    MB1(6); ISSUE1(kt + 4, kt & 3);       RD1((kt + 1) & 3, AY, BY); MF1(AX, BX);
    MB1(6); ISSUE1(kt + 5, (kt + 1) & 3); RD1((kt + 2) & 3, AX, BX); MF1(AY, BY);
  }
  MB1(6); RD1(1, AY, BY); MF1(AX, BX);
  MB1(3); RD1(2, AX, BX); MF1(AY, BY);
  MB1(0); RD1(3, AY, BY); MF1(AX, BX);
  MF1(AY, BY);

  float scl[4], sft[4];
#pragma unroll
  for (int j = 0; j < 4; ++j) {
    const int c = n0 + wn * 64 + j * 16 + r15;
    scl[j] = job.scl[c];
    sft[j] = job.sft[c];
  }
  const int rbase = m0 + wm * 64 + (lane >> 4) * 4;

  if (job.epi == 4) {
    __syncthreads();
    unsigned short* lds = &ABS[0][0];
    const int gq = lane >> 4;
#pragma unroll
    for (int i = 0; i < 4; ++i) {
      const int n_loc = wm * 16 + 4 * i + gq;
#pragma unroll
      for (int j = 0; j < 4; ++j) {
        const int c_loc = wn * 64 + j * 16 + r15;
        const int colbase = c_loc * 32 + (n_loc ^ (((c_loc >> 2) & 3) << 3));
#pragma unroll
        for (int r = 0; r < 4; ++r)
          lds[r * 8192 + colbase] = f2bf(acc[i][j][r] * scl[j] + sft[j]);
      }
    }
    __syncthreads();
    const int b = panel >> 5, n0g = (panel & 31) * 32;
#pragma unroll
    for (int it = 0; it < 8; ++it) {
      const int rho = wv * 128 + it * 16 + (lane >> 2);
      const int t = rho >> 8, c = rho & 255;
      const int nb = lane & 3;
      const uint4 d = *(const uint4*)&lds[t * 8192 + c * 32 + ((nb ^ ((c >> 2) & 3)) << 3)];
      *(uint4*)(job.out16b + (size_t)((t * 4 + b) * 512 + n0 + c) * 1024 + n0g + nb * 8) = d;
    }
  } else {
#pragma unroll
    for (int i = 0; i < 4; ++i)
#pragma unroll
      for (int r = 0; r < 4; ++r) {
        const int mp = rbase + 16 * i + r;
        const int t = mp & 3, bn = mp >> 2;
        const int mstd = (((t << 2) | (bn >> 10)) << 10) | (bn & 1023);
        float* prow = job.out32 + (size_t)mstd * 512 + n0 + wn * 64 + r15;
#pragma unroll
        for (int j = 0; j < 4; ++j) prow[j * 16] = acc[i][j][r] * scl[j] + sft[j];
      }
  }
}

// merged qk+v dispatch: blocks 0..255 qk, 256..511 v (backfills qk tail)
__global__ __launch_bounds__(512, 2) void gemm_fused(Job2 jqk, Job2 jv) {
  __shared__ unsigned short AB[4][256 * 64];   // 128 KB
  if (blockIdx.x < 256) qk_body(jqk, blockIdx.x, AB);
  else                  v_body(jv, blockIdx.x - 256, (unsigned short (*)[384 * 32])AB);
}

// standalone 128x256 (proj)
__global__ __launch_bounds__(512, 2) void gemm128(Job2 job) {
  __shared__ unsigned short ABS[4][384 * 32];  // 96 KB
  v_body(job, blockIdx.x, ABS);
}

// ---------------------------------------------------------------------------
// kv_gemm with fused reduction (r10 form): 128 blocks = 1 head, 4 waves x
// 256 m, sequential barrier-ordered LDS reduce, ->kvt bf16.
// ---------------------------------------------------------------------------
__global__ __launch_bounds__(256) void kv_gemm(const unsigned short* __restrict__ ktr,
                                               const unsigned short* __restrict__ vtr,
                                               unsigned short* __restrict__ kvt) {
  const int head = blockIdx.x;
  const int tb = head >> 3;
  const int h = head & 7;
  const int wv = threadIdx.x >> 6, lane = threadIdx.x & 63;
  const int m0 = wv * 256;
  const size_t cbase = (size_t)tb * C_ + h * 64;
  const int rsel = lane & 15, koff = (lane >> 4) * 8;

  floatx4 acc[4][4];
#pragma unroll
  for (int i = 0; i < 4; ++i)
#pragma unroll
    for (int j = 0; j < 4; ++j) acc[i][j] = floatx4{0.f, 0.f, 0.f, 0.f};

#pragma unroll
  for (int s = 0; s < 8; ++s) {
    const int m = m0 + s * 32 + koff;
    bf16x8 a[4], b[4];
#pragma unroll
    for (int dt = 0; dt < 4; ++dt)
      a[dt] = *(const bf16x8*)(ktr + (cbase + dt * 16 + rsel) * N_ + m);
#pragma unroll
    for (int et = 0; et < 4; ++et)
      b[et] = *(const bf16x8*)(vtr + (cbase + et * 16 + rsel) * N_ + m);
#pragma unroll
    for (int dt = 0; dt < 4; ++dt)
#pragma unroll
      for (int et = 0; et < 4; ++et)
        acc[dt][et] = __builtin_amdgcn_mfma_f32_16x16x32_bf16(a[dt], b[et], acc[dt][et], 0, 0, 0);
  }

  __shared__ float red[4096];
  const int dbase = (lane >> 4) * 4;
  const int e0 = lane & 15;
#pragma unroll 1
  for (int w = 0; w < 4; ++w) {
    if (wv == w) {
#pragma unroll
      for (int dt = 0; dt < 4; ++dt)
#pragma unroll
        for (int et = 0; et < 4; ++et)
#pragma unroll
          for (int r = 0; r < 4; ++r) {
            const int o = (dt * 16 + dbase + r) * 64 + et * 16 + e0;
            red[o] = (w == 0) ? acc[dt][et][r] : red[o] + acc[dt][et][r];
          }
    }
    __syncthreads();
  }
  const int d = threadIdx.x & 63;
  const int eg = threadIdx.x >> 6;
#pragma unroll
  for (int j = 0; j < 16; ++j) {
    const int e = eg * 16 + j;
    kvt[(size_t)head * 4096 + e * 64 + d] = f2bf(0.125f * red[d * 64 + e]);
  }
}

// ---------------------------------------------------------------------------
// av (r10 form): O rows in m' layout. 256 blocks; 4 heads per block.
// ---------------------------------------------------------------------------
__global__ __launch_bounds__(256) void av_gemm(const unsigned short* __restrict__ qs,
                                               const unsigned short* __restrict__ kvt,
                                               unsigned short* __restrict__ obuf) {
  const int bx = blockIdx.x;
  const int tb = bx >> 4;
  const int sub = bx & 15;
  const int nt = sub >> 1;
  const int h0 = (sub & 1) * 4;
  const int t = tb >> 2, b = tb & 3;
  const int wv = threadIdx.x >> 6, lane = threadIdx.x & 63;
  const int n0 = nt * 128 + wv * 32;
  const int rsel = lane & 15, koff = (lane >> 4) * 8;

#pragma unroll 1
  for (int h = h0; h < h0 + 4; ++h) {
    floatx4 acc[2][4];
#pragma unroll
    for (int i = 0; i < 2; ++i)
#pragma unroll
      for (int j = 0; j < 4; ++j) acc[i][j] = floatx4{0.f, 0.f, 0.f, 0.f};
    const unsigned short* kvh = kvt + ((size_t)tb * 8 + h) * 4096;
#pragma unroll
    for (int s = 0; s < 2; ++s) {
      bf16x8 a[2], bv[4];
#pragma unroll
      for (int i = 0; i < 2; ++i) {
        const int n = n0 + i * 16 + rsel;
        a[i] = *(const bf16x8*)(qs + (size_t)((((b << 10) | n) << 2) | t) * 512 + h * 64 + s * 32 + koff);
      }
#pragma unroll
      for (int et = 0; et < 4; ++et)
        bv[et] = *(const bf16x8*)(kvh + (et * 16 + rsel) * 64 + s * 32 + koff);
#pragma unroll
      for (int i = 0; i < 2; ++i)
#pragma unroll
        for (int et = 0; et < 4; ++et)
          acc[i][et] = __builtin_amdgcn_mfma_f32_16x16x32_bf16(a[i], bv[et], acc[i][et], 0, 0, 0);
    }
#pragma unroll
    for (int i = 0; i < 2; ++i)
#pragma unroll
      for (int et = 0; et < 4; ++et)
#pragma unroll
        for (int r = 0; r < 4; ++r) {
          const int n = n0 + i * 16 + (lane >> 4) * 4 + r;
          obuf[(size_t)((((b << 10) | n) << 2) | t) * 512 + h * 64 + et * 16 + rsel] = f2bf(acc[i][et][r]);
        }
  }
}

// ---------------------------------------------------------------------------
extern "C" void kernel_launch(void* const* d_in, const int* in_sizes, int n_in,
                              void* d_out, int out_size, void* d_ws, size_t ws_size,
                              hipStream_t stream) {
  char* ws = (char*)d_ws;
  unsigned short* X2   = (unsigned short*)(ws + 0);            // 32 MB [m'][1024]
  unsigned short* Wqk3 = (unsigned short*)(ws + 33554432ull);  // 3 MB
  unsigned short* Wvb  = (unsigned short*)(ws + 36700160ull);  // 0.5 MB
  unsigned short* Wpb  = (unsigned short*)(ws + 37224448ull);  // 0.5 MB
  float*          scl  = (float*)(ws + 37748736ull);           // 8 KB
  float*          sft  = (float*)(ws + 37756928ull);           // 8 KB
  unsigned short* qsb  = (unsigned short*)(ws + 41943040ull);  // 16 MB [m'][512]
  unsigned short* ktr  = (unsigned short*)(ws + 58720256ull);  // 16 MB [t,b,c,n]
  unsigned short* vtr  = (unsigned short*)(ws + 75497472ull);  // 16 MB [t,b,c,n]
  unsigned short* kvt  = (unsigned short*)(ws + 92274688ull);  // 1 MB
  unsigned short* ob   = (unsigned short*)(ws + 93323264ull);  // 16 MB [m'][512]

  PrepArgs pa;
  pa.x  = (const float*)d_in[0];
  pa.qw = (const float*)d_in[2];
  pa.kw = (const float*)d_in[8];
  pa.vw = (const float*)d_in[14];
  pa.pw = (const float*)d_in[20];
  pa.X2 = X2; pa.Wqk3 = Wqk3; pa.Wvb = Wvb; pa.Wpb = Wpb;
  pa.scl = scl; pa.sft = sft;
  pa.bp.p[0]=(const float*)d_in[3];  pa.bp.p[1]=(const float*)d_in[4];  pa.bp.p[2]=(const float*)d_in[5];  pa.bp.p[3]=(const float*)d_in[6];  pa.bp.p[4]=(const float*)d_in[7];
  pa.bp.p[5]=(const float*)d_in[9];  pa.bp.p[6]=(const float*)d_in[10]; pa.bp.p[7]=(const float*)d_in[11]; pa.bp.p[8]=(const float*)d_in[12]; pa.bp.p[9]=(const float*)d_in[13];
  pa.bp.p[10]=(const float*)d_in[15];pa.bp.p[11]=(const float*)d_in[16];pa.bp.p[12]=(const float*)d_in[17];pa.bp.p[13]=(const float*)d_in[18];pa.bp.p[14]=(const float*)d_in[19];
  pa.bp.p[15]=(const float*)d_in[21];pa.bp.p[16]=(const float*)d_in[22];pa.bp.p[17]=(const float*)d_in[23];pa.bp.p[18]=(const float*)d_in[24];pa.bp.p[19]=(const float*)d_in[25];
  prep_all<<<dim3(9224), 256, 0, stream>>>(pa);

  Job2 jqk{X2, 1024, Wqk3, 1536, 1536, 512, 2, scl, sft, nullptr, qsb, ktr};
  Job2 jv {X2, 1024, Wvb,  512,  512,  512, 4, scl + 1024, sft + 1024, nullptr, nullptr, vtr};
  gemm_fused<<<dim3(512), 512, 0, stream>>>(jqk, jv);

  kv_gemm<<<dim3(128), 256, 0, stream>>>(ktr, vtr, kvt);
  av_gemm<<<dim3(256), 256, 0, stream>>>(qsb, kvt, ob);

  Job2 jp{ob, 512, Wpb, 512, 512, 512, 3, scl + 1536, sft + 1536, (float*)d_out, nullptr, nullptr};
  gemm128<<<dim3(256), 512, 0, stream>>>(jp);
}

// Round 13
// 122.082 us; speedup vs baseline: 1.6219x; 1.6219x over previous
//
#include <hip/hip_runtime.h>

// SSA forward, f32 I/O:
//   q = heads(lif(bn(x Wq^T))), k = heads(lif(bn(x Wk^T))), v = heads(bn(x Wv^T))
//   o = 0.125 * q @ (k^T v)   (no softmax -> associativity), out = bn(o Wp^T)
// Q/K GEMMs: 3-term bf16 split (xh*wh + xl*wh + xh*wl) for ~f32 accuracy.
// Row permutation m' = ((b*N+n)*T + t): LIF fused in GEMM epilogue; k/v
// written directly transposed [t,b,c,n] via LDS-transpose epilogue.
// qk GEMM slot machine: depth-4 prefetch, counted vmcnt(8), phase-balanced
// ds_reads (6+6 per slot). qk+v merged in one 512-block dispatch.
// 5 dispatches. [r13 = exact revert to best-known r10 config, 122.1 us]

#define T_ 4
#define B_ 4
#define N_ 1024
#define C_ 512
#define H_ 8
#define M_ (T_*B_*N_)   // 16384

typedef __bf16 bf16x8 __attribute__((ext_vector_type(8)));
typedef float  floatx4 __attribute__((ext_vector_type(4)));

__device__ __forceinline__ float bf2f(unsigned short u) {
  union { unsigned int i; float f; } v; v.i = ((unsigned int)u) << 16; return v.f;
}
__device__ __forceinline__ unsigned short f2bf(float f) {
  unsigned int x = __float_as_uint(f);
  return (unsigned short)((x + 0x7fffu + ((x >> 16) & 1u)) >> 16);  // RNE
}

#define GLOAD16(gaddr, ldsbase) \
  __builtin_amdgcn_global_load_lds((__attribute__((address_space(1))) void*)(gaddr), \
                                   (__attribute__((address_space(3))) void*)(ldsbase), 16, 0, 0)

struct BnParams { const float* p[20]; };
struct PrepArgs {
  const float *x, *qw, *kw, *vw, *pw;
  unsigned short *X2, *Wqk3, *Wvb, *Wpb;
  float *scl, *sft;
  BnParams bp;
};

// One dispatch: blocks [0,8192) x-split, [8192,9216) weights, [9216,9224) bn.
__global__ __launch_bounds__(256) void prep_all(PrepArgs P) {
  const int bid = blockIdx.x;
  if (bid < 8192) {
    const int idx = (bid * 256 + threadIdx.x) * 4;
    const float4 v = *(const float4*)(P.x + idx);
    const int m = idx >> 9, k = idx & 511;
    const int t = m >> 12, b = (m >> 10) & 3, n = m & 1023;
    const int mp = (((b << 10) | n) << 2) | t;
    const size_t base = (size_t)mp * 1024 + k;
    float vv[4] = {v.x, v.y, v.z, v.w};
    unsigned short h[4], l[4];
#pragma unroll
    for (int j = 0; j < 4; ++j) { h[j] = f2bf(vv[j]); l[j] = f2bf(vv[j] - bf2f(h[j])); }
    *(ushort4*)(P.X2 + base) = ushort4{h[0], h[1], h[2], h[3]};
    *(ushort4*)(P.X2 + base + 512) = ushort4{l[0], l[1], l[2], l[3]};
  } else if (bid < 9216) {
    const int z = (bid - 8192) >> 8;
    const int idx = ((((bid - 8192) & 255) * 256) + threadIdx.x) * 4;
    const float* src = (z == 0) ? P.qw : (z == 1) ? P.kw : (z == 2) ? P.vw : P.pw;
    const float4 v = *(const float4*)(src + idx);
    if (z >= 2) {
      unsigned short* dst = (z == 2) ? P.Wvb : P.Wpb;
      *(ushort4*)(dst + idx) = ushort4{f2bf(v.x), f2bf(v.y), f2bf(v.z), f2bf(v.w)};
      return;
    }
    const int row = idx >> 9, k = idx & 511;
    unsigned short* dst = P.Wqk3 + (size_t)(z * 512) * 1536;
    const size_t base = (size_t)row * 1536 + k;
    float vv[4] = {v.x, v.y, v.z, v.w};
    unsigned short h[4], l[4];
#pragma unroll
    for (int j = 0; j < 4; ++j) { h[j] = f2bf(vv[j]); l[j] = f2bf(vv[j] - bf2f(h[j])); }
    ushort4 hi{h[0], h[1], h[2], h[3]};
    *(ushort4*)(dst + base) = hi;
    *(ushort4*)(dst + base + 512) = hi;
    *(ushort4*)(dst + base + 1024) = ushort4{l[0], l[1], l[2], l[3]};
  } else {
    const int o = (bid - 9216) * 256 + threadIdx.x;
    const int grp = o >> 9, ci = o & 511;
    const float s = P.bp.p[grp * 5 + 1][ci] * rsqrtf(P.bp.p[grp * 5 + 4][ci] + 1e-5f);
    P.scl[o] = s;
    P.sft[o] = (P.bp.p[grp * 5 + 0][ci] - P.bp.p[grp * 5 + 3][ci]) * s + P.bp.p[grp * 5 + 2][ci];
  }
}

struct Job2 {
  const unsigned short* A; int lda;
  const unsigned short* w; int ldb;
  int K, ldc, epi;  // epi: 2=qk dual (q->qsb, k->LDS-transpose->ktr)
                    //      3=f32 unpermuted, 4=bf16 LDS-transpose (v->vtr)
  const float* scl; const float* sft;
  float* out32; unsigned short* out16; unsigned short* out16b;
};

// ---------------------------------------------------------------------------
// qk body: 256x256, BK=32, depth-4, phase-balanced 6+6 ds_reads per slot.
// ---------------------------------------------------------------------------
__device__ __forceinline__ void qk_body(const Job2& job, int bx,
                                        unsigned short (*AB)[256 * 64]) {
  const int xcd = bx & 7, slot = bx >> 3;
  const int panel = xcd + 8 * (slot >> 2);
  const int m0 = panel * 256;
  const int n0 = (slot & 3) * 256;

  const int tid = threadIdx.x;
  const int wv = tid >> 6, lane = tid & 63;
  const int wm = wv >> 1, wn = wv & 1;
  const int NT = job.K >> 5;   // 48

  const int rloc = lane >> 3;
  const int ulog = (lane & 7) ^ rloc;
  const bool isA = ulog < 4;
  const unsigned short* bq[4];
#pragma unroll
  for (int q = 0; q < 4; ++q) {
    const int row = wv * 32 + q * 8 + rloc;
    bq[q] = isA ? job.A + (size_t)(m0 + row) * job.lda + ulog * 8
                : job.w + (size_t)(n0 + row) * job.ldb + (ulog - 4) * 8;
  }

#define ISSUE(T_, BUF_) do {                                                 \
    const int t_ = (T_);                                                     \
    const int off_ = isA ? ((t_ < 32 ? t_ : t_ - 32) << 5) : (t_ << 5);      \
    _Pragma("unroll")                                                        \
    for (int q = 0; q < 4; ++q)                                              \
      GLOAD16(bq[q] + off_, &AB[BUF_][(wv * 32 + q * 8) * 64]);              \
  } while (0)

  const int r15 = lane & 15;
  const int apos = (lane >> 4) ^ (lane & 7);
  const int bpos = (4 | (lane >> 4)) ^ (lane & 7);
  const int aoff = (wm * 64 + r15) * 64 + apos * 8;
  const int boff = (wn * 128 + r15) * 64 + bpos * 8;

  bf16x8 A0[4], A1[4], L0[4], L1[4], Hh[4];

#define RD_A_L01(BUF_, AX, LX) do {                                          \
    const unsigned short* lb_ = &AB[BUF_][0];                                \
    _Pragma("unroll")                                                        \
    for (int i_ = 0; i_ < 4; ++i_) AX[i_] = *(const bf16x8*)(lb_ + aoff + i_ * 1024); \
    LX[0] = *(const bf16x8*)(lb_ + boff);                                    \
    LX[1] = *(const bf16x8*)(lb_ + boff + 1024);                             \
  } while (0)

#define RD_L23_HI(BUF_, LX) do {                                             \
    const unsigned short* lb_ = &AB[BUF_][0];                                \
    LX[2] = *(const bf16x8*)(lb_ + boff + 2 * 1024);                         \
    LX[3] = *(const bf16x8*)(lb_ + boff + 3 * 1024);                         \
    _Pragma("unroll")                                                        \
    for (int j_ = 0; j_ < 4; ++j_) Hh[j_] = *(const bf16x8*)(lb_ + boff + (4 + j_) * 1024); \
  } while (0)

#define MF_LO(AX, LX) do {                                                   \
    __builtin_amdgcn_s_setprio(1);                                           \
    _Pragma("unroll")                                                        \
    for (int j_ = 0; j_ < 4; ++j_)                                           \
    _Pragma("unroll")                                                        \
      for (int i_ = 0; i_ < 4; ++i_)                                         \
        acc[i_][j_] = __builtin_amdgcn_mfma_f32_16x16x32_bf16(AX[i_], LX[j_], acc[i_][j_], 0, 0, 0); \
    __builtin_amdgcn_s_setprio(0);                                           \
  } while (0)

#define MF_HI(AX) do {                                                       \
    __builtin_amdgcn_s_setprio(1);                                           \
    _Pragma("unroll")                                                        \
    for (int i_ = 0; i_ < 4; ++i_)                                           \
    _Pragma("unroll")                                                        \
      for (int j_ = 0; j_ < 4; ++j_)                                         \
        acc[i_][4 + j_] = __builtin_amdgcn_mfma_f32_16x16x32_bf16(AX[i_], Hh[j_], acc[i_][4 + j_], 0, 0, 0); \
    __builtin_amdgcn_s_setprio(0);                                           \
  } while (0)

#define MIDBAR(N_) do {                                                      \
    asm volatile("s_waitcnt vmcnt(" #N_ ")" ::: "memory");                   \
    __builtin_amdgcn_s_barrier();                                            \
    __builtin_amdgcn_sched_barrier(0);                                       \
  } while (0)

#define SLOT_I(KT_, BC_, BN_, AX, LX, AY, LY) do {                           \
    RD_L23_HI(BC_, LX); MF_LO(AX, LX);                                       \
    MIDBAR(8);                                                               \
    ISSUE((KT_) + 4, BC_);                                                   \
    RD_A_L01(BN_, AY, LY); MF_HI(AX);                                        \
  } while (0)

  floatx4 acc[4][8];
#pragma unroll
  for (int i = 0; i < 4; ++i)
#pragma unroll
    for (int j = 0; j < 8; ++j) acc[i][j] = floatx4{0.f, 0.f, 0.f, 0.f};

  ISSUE(0, 0); ISSUE(1, 1); ISSUE(2, 2); ISSUE(3, 3);
  asm volatile("s_waitcnt vmcnt(12)" ::: "memory");
  __builtin_amdgcn_s_barrier();
  __builtin_amdgcn_sched_barrier(0);
  RD_A_L01(0, A0, L0);

  const int NG = (NT - 4) >> 2;
  for (int g = 0; g < NG; ++g) {
    const int g4 = g << 2;
    SLOT_I(g4 + 0, 0, 1, A0, L0, A1, L1);
    SLOT_I(g4 + 1, 1, 2, A1, L1, A0, L0);
    SLOT_I(g4 + 2, 2, 3, A0, L0, A1, L1);
    SLOT_I(g4 + 3, 3, 0, A1, L1, A0, L0);
  }
  RD_L23_HI(0, L0); MF_LO(A0, L0); MIDBAR(8); RD_A_L01(1, A1, L1); MF_HI(A0);
  RD_L23_HI(1, L1); MF_LO(A1, L1); MIDBAR(4); RD_A_L01(2, A0, L0); MF_HI(A1);
  RD_L23_HI(2, L0); MF_LO(A0, L0); MIDBAR(0); RD_A_L01(3, A1, L1); MF_HI(A0);
  RD_L23_HI(3, L1); MF_LO(A1, L1); MF_HI(A1);

  // ---- epilogue
  float scl[8], sft[8];
#pragma unroll
  for (int j = 0; j < 8; ++j) {
    const int c = n0 + wn * 128 + j * 16 + r15;
    scl[j] = job.scl[c];
    sft[j] = job.sft[c];
  }
  const int rbase = m0 + wm * 64 + (lane >> 4) * 4;

  if (n0 < 512) {
    // q half: BN -> in-register LIF -> qsb [m'][512]
    const int cb = n0 + wn * 128 + r15;
#pragma unroll
    for (int i = 0; i < 4; ++i) {
      unsigned short spk[4][8];
#pragma unroll
      for (int j = 0; j < 8; ++j) {
        float vme = 0.f;
#pragma unroll
        for (int r = 0; r < 4; ++r) {
          const float y = acc[i][j][r] * scl[j] + sft[j];
          vme += (y - vme) * 0.5f;
          const bool sp = vme >= 1.0f;
          spk[r][j] = sp ? (unsigned short)0x3F80 : (unsigned short)0;
          if (sp) vme = 0.f;
        }
      }
#pragma unroll
      for (int r = 0; r < 4; ++r) {
        unsigned short* prow = job.out16 + (size_t)(rbase + 16 * i + r) * 512 + cb;
#pragma unroll
        for (int j = 0; j < 8; ++j) prow[j * 16] = spk[r][j];
      }
    }
  } else {
    // k half: BN -> LIF -> LDS [4t][256c][64n] (swizzled) -> ktr [t,b,c,n]
    __syncthreads();
    unsigned short* lds = &AB[0][0];
    const int gq = lane >> 4;
#pragma unroll
    for (int i = 0; i < 4; ++i) {
      const int n_loc = wm * 16 + 4 * i + gq;
#pragma unroll
      for (int j = 0; j < 8; ++j) {
        const int c_loc = wn * 128 + j * 16 + r15;
        const int colbase = c_loc * 64 + (n_loc ^ ((c_loc & 7) << 3));
        float vme = 0.f;
#pragma unroll
        for (int r = 0; r < 4; ++r) {
          const float y = acc[i][j][r] * scl[j] + sft[j];
          vme += (y - vme) * 0.5f;
          const bool sp = vme >= 1.0f;
          lds[r * 16384 + colbase] = sp ? (unsigned short)0x3F80 : (unsigned short)0;
          if (sp) vme = 0.f;
        }
      }
    }
    __syncthreads();
    const int b = panel >> 4, n0g = (panel & 15) * 64, cb = n0 - 512;
#pragma unroll
    for (int it = 0; it < 16; ++it) {
      const int rho = wv * 128 + it * 8 + (lane >> 3);
      const int t = rho >> 8, c = rho & 255;
      const int nb = lane & 7;
      const uint4 d = *(const uint4*)&lds[t * 16384 + c * 64 + ((nb ^ (c & 7)) << 3)];
      *(uint4*)(job.out16b + (size_t)((t * 4 + b) * 512 + cb + c) * 1024 + n0g + nb * 8) = d;
    }
  }
}

// ---------------------------------------------------------------------------
// 128x256 body (v/proj): K=512 (NT=16). Depth-4 prefetch.
// ---------------------------------------------------------------------------
__device__ __forceinline__ void v_body(const Job2& job, int bx,
                                       unsigned short (*ABS)[384 * 32]) {
  const int xcd = bx & 7, slot = bx >> 3;
  const int panel = xcd + 8 * (slot >> 1);
  const int m0 = panel * 128;
  const int n0 = (slot & 1) * 256;

  const int tid = threadIdx.x;
  const int wv = tid >> 6, lane = tid & 63;
  const int wm = wv >> 2, wn = wv & 3;

  const unsigned short* src[3];
#pragma unroll
  for (int g = 0; g < 3; ++g) {
    const int row = wv * 48 + g * 16 + (lane >> 2);
    const int ulog = (lane & 3) ^ (row & 3);
    src[g] = (row < 128) ? job.A + (size_t)(m0 + row) * job.lda + ulog * 8
                         : job.w + (size_t)(n0 + row - 128) * job.ldb + ulog * 8;
  }

#define ISSUE1(T_, BUF_) do {                                                \
    const int k0_ = (T_) << 5;                                               \
    _Pragma("unroll")                                                        \
    for (int g_ = 0; g_ < 3; ++g_)                                           \
      GLOAD16(src[g_] + k0_, &ABS[BUF_][(wv * 48 + g_ * 16) * 32]);          \
  } while (0)

  const int r15 = lane & 15;
  const int uoff = ((lane >> 4) ^ (r15 & 3)) << 3;
  const int arow0 = (wm * 64 + r15) * 32 + uoff;
  const int brow0 = (128 + wn * 64 + r15) * 32 + uoff;

  bf16x8 AX[4], BX[4], AY[4], BY[4];
#define RD1(BUF_, A_, B_) do {                                               \
    const unsigned short* lb_ = &ABS[BUF_][0];                               \
    _Pragma("unroll")                                                        \
    for (int i_ = 0; i_ < 4; ++i_) A_[i_] = *(const bf16x8*)(lb_ + arow0 + i_ * 512); \
    _Pragma("unroll")                                                        \
    for (int j_ = 0; j_ < 4; ++j_) B_[j_] = *(const bf16x8*)(lb_ + brow0 + j_ * 512); \
  } while (0)

#define MF1(A_, B_) do {                                                     \
    __builtin_amdgcn_s_setprio(1);                                           \
    _Pragma("unroll")                                                        \
    for (int i_ = 0; i_ < 4; ++i_)                                           \
    _Pragma("unroll")                                                        \
      for (int j_ = 0; j_ < 4; ++j_)                                         \
        acc[i_][j_] = __builtin_amdgcn_mfma_f32_16x16x32_bf16(A_[i_], B_[j_], acc[i_][j_], 0, 0, 0); \
    __builtin_amdgcn_s_setprio(0);                                           \
  } while (0)

#define MB1(N_) do {                                                         \
    asm volatile("s_waitcnt vmcnt(" #N_ ")" ::: "memory");                   \
    __builtin_amdgcn_s_barrier();                                            \
    __builtin_amdgcn_sched_barrier(0);                                       \
  } while (0)

  floatx4 acc[4][4];
#pragma unroll
  for (int i = 0; i < 4; ++i)
#pragma unroll
    for (int j = 0; j < 4; ++j) acc[i][j] = floatx4{0.f, 0.f, 0.f, 0.f};

  ISSUE1(0, 0); ISSUE1(1, 1); ISSUE1(2, 2); ISSUE1(3, 3);
  asm volatile("s_waitcnt vmcnt(9)" ::: "memory");
  __builtin_amdgcn_s_barrier();
  __builtin_amdgcn_sched_barrier(0);
  RD1(0, AX, BX);

#pragma unroll 1
  for (int kt = 0; kt < 12; kt += 2) {
    MB1(6); ISSUE1(kt + 4, kt & 3);       RD1((kt + 1) & 3, AY, BY); MF1(AX, BX);
    MB1(6); ISSUE1(kt + 5, (kt + 1) & 3); RD1((kt + 2) & 3, AX, BX); MF1(AY, BY);
  }
  MB1(6); RD1(1, AY, BY); MF1(AX, BX);
  MB1(3); RD1(2, AX, BX); MF1(AY, BY);
  MB1(0); RD1(3, AY, BY); MF1(AX, BX);
  MF1(AY, BY);

  float scl[4], sft[4];
#pragma unroll
  for (int j = 0; j < 4; ++j) {
    const int c = n0 + wn * 64 + j * 16 + r15;
    scl[j] = job.scl[c];
    sft[j] = job.sft[c];
  }
  const int rbase = m0 + wm * 64 + (lane >> 4) * 4;

  if (job.epi == 4) {
    __syncthreads();
    unsigned short* lds = &ABS[0][0];
    const int gq = lane >> 4;
#pragma unroll
    for (int i = 0; i < 4; ++i) {
      const int n_loc = wm * 16 + 4 * i + gq;
#pragma unroll
      for (int j = 0; j < 4; ++j) {
        const int c_loc = wn * 64 + j * 16 + r15;
        const int colbase = c_loc * 32 + (n_loc ^ (((c_loc >> 2) & 3) << 3));
#pragma unroll
        for (int r = 0; r < 4; ++r)
          lds[r * 8192 + colbase] = f2bf(acc[i][j][r] * scl[j] + sft[j]);
      }
    }
    __syncthreads();
    const int b = panel >> 5, n0g = (panel & 31) * 32;
#pragma unroll
    for (int it = 0; it < 8; ++it) {
      const int rho = wv * 128 + it * 16 + (lane >> 2);
      const int t = rho >> 8, c = rho & 255;
      const int nb = lane & 3;
      const uint4 d = *(const uint4*)&lds[t * 8192 + c * 32 + ((nb ^ ((c >> 2) & 3)) << 3)];
      *(uint4*)(job.out16b + (size_t)((t * 4 + b) * 512 + n0 + c) * 1024 + n0g + nb * 8) = d;
    }
  } else {
#pragma unroll
    for (int i = 0; i < 4; ++i)
#pragma unroll
      for (int r = 0; r < 4; ++r) {
        const int mp = rbase + 16 * i + r;
        const int t = mp & 3, bn = mp >> 2;
        const int mstd = (((t << 2) | (bn >> 10)) << 10) | (bn & 1023);
        float* prow = job.out32 + (size_t)mstd * 512 + n0 + wn * 64 + r15;
#pragma unroll
        for (int j = 0; j < 4; ++j) prow[j * 16] = acc[i][j][r] * scl[j] + sft[j];
      }
  }
}

// merged qk+v dispatch: blocks 0..255 qk, 256..511 v (backfills qk tail)
__global__ __launch_bounds__(512, 2) void gemm_fused(Job2 jqk, Job2 jv) {
  __shared__ unsigned short AB[4][256 * 64];   // 128 KB
  if (blockIdx.x < 256) qk_body(jqk, blockIdx.x, AB);
  else                  v_body(jv, blockIdx.x - 256, (unsigned short (*)[384 * 32])AB);
}

// standalone 128x256 (proj)
__global__ __launch_bounds__(512, 2) void gemm128(Job2 job) {
  __shared__ unsigned short ABS[4][384 * 32];  // 96 KB
  v_body(job, blockIdx.x, ABS);
}

// ---------------------------------------------------------------------------
// kv_gemm with fused reduction: 128 blocks = 1 head, 4 waves x 256 m,
// sequential barrier-ordered LDS reduce (deterministic), ->kvt bf16.
// ---------------------------------------------------------------------------
__global__ __launch_bounds__(256) void kv_gemm(const unsigned short* __restrict__ ktr,
                                               const unsigned short* __restrict__ vtr,
                                               unsigned short* __restrict__ kvt) {
  const int head = blockIdx.x;
  const int tb = head >> 3;
  const int h = head & 7;
  const int wv = threadIdx.x >> 6, lane = threadIdx.x & 63;
  const int m0 = wv * 256;
  const size_t cbase = (size_t)tb * C_ + h * 64;
  const int rsel = lane & 15, koff = (lane >> 4) * 8;

  floatx4 acc[4][4];
#pragma unroll
  for (int i = 0; i < 4; ++i)
#pragma unroll
    for (int j = 0; j < 4; ++j) acc[i][j] = floatx4{0.f, 0.f, 0.f, 0.f};

#pragma unroll
  for (int s = 0; s < 8; ++s) {
    const int m = m0 + s * 32 + koff;
    bf16x8 a[4], b[4];
#pragma unroll
    for (int dt = 0; dt < 4; ++dt)
      a[dt] = *(const bf16x8*)(ktr + (cbase + dt * 16 + rsel) * N_ + m);
#pragma unroll
    for (int et = 0; et < 4; ++et)
      b[et] = *(const bf16x8*)(vtr + (cbase + et * 16 + rsel) * N_ + m);
#pragma unroll
    for (int dt = 0; dt < 4; ++dt)
#pragma unroll
      for (int et = 0; et < 4; ++et)
        acc[dt][et] = __builtin_amdgcn_mfma_f32_16x16x32_bf16(a[dt], b[et], acc[dt][et], 0, 0, 0);
  }

  __shared__ float red[4096];
  const int dbase = (lane >> 4) * 4;
  const int e0 = lane & 15;
#pragma unroll 1
  for (int w = 0; w < 4; ++w) {
    if (wv == w) {
#pragma unroll
      for (int dt = 0; dt < 4; ++dt)
#pragma unroll
        for (int et = 0; et < 4; ++et)
#pragma unroll
          for (int r = 0; r < 4; ++r) {
            const int o = (dt * 16 + dbase + r) * 64 + et * 16 + e0;
            red[o] = (w == 0) ? acc[dt][et][r] : red[o] + acc[dt][et][r];
          }
    }
    __syncthreads();
  }
  const int d = threadIdx.x & 63;
  const int eg = threadIdx.x >> 6;
#pragma unroll
  for (int j = 0; j < 16; ++j) {
    const int e = eg * 16 + j;
    kvt[(size_t)head * 4096 + e * 64 + d] = f2bf(0.125f * red[d * 64 + e]);
  }
}

// ---------------------------------------------------------------------------
// av: O rows in m' layout. 256 blocks; 4 heads per block.
// ---------------------------------------------------------------------------
__global__ __launch_bounds__(256) void av_gemm(const unsigned short* __restrict__ qs,
                                               const unsigned short* __restrict__ kvt,
                                               unsigned short* __restrict__ obuf) {
  const int bx = blockIdx.x;
  const int tb = bx >> 4;
  const int sub = bx & 15;
  const int nt = sub >> 1;
  const int h0 = (sub & 1) * 4;
  const int t = tb >> 2, b = tb & 3;
  const int wv = threadIdx.x >> 6, lane = threadIdx.x & 63;
  const int n0 = nt * 128 + wv * 32;
  const int rsel = lane & 15, koff = (lane >> 4) * 8;

#pragma unroll 1
  for (int h = h0; h < h0 + 4; ++h) {
    floatx4 acc[2][4];
#pragma unroll
    for (int i = 0; i < 2; ++i)
#pragma unroll
      for (int j = 0; j < 4; ++j) acc[i][j] = floatx4{0.f, 0.f, 0.f, 0.f};
    const unsigned short* kvh = kvt + ((size_t)tb * 8 + h) * 4096;
#pragma unroll
    for (int s = 0; s < 2; ++s) {
      bf16x8 a[2], bv[4];
#pragma unroll
      for (int i = 0; i < 2; ++i) {
        const int n = n0 + i * 16 + rsel;
        a[i] = *(const bf16x8*)(qs + (size_t)((((b << 10) | n) << 2) | t) * 512 + h * 64 + s * 32 + koff);
      }
#pragma unroll
      for (int et = 0; et < 4; ++et)
        bv[et] = *(const bf16x8*)(kvh + (et * 16 + rsel) * 64 + s * 32 + koff);
#pragma unroll
      for (int i = 0; i < 2; ++i)
#pragma unroll
        for (int et = 0; et < 4; ++et)
          acc[i][et] = __builtin_amdgcn_mfma_f32_16x16x32_bf16(a[i], bv[et], acc[i][et], 0, 0, 0);
    }
#pragma unroll
    for (int i = 0; i < 2; ++i)
#pragma unroll
      for (int et = 0; et < 4; ++et)
#pragma unroll
        for (int r = 0; r < 4; ++r) {
          const int n = n0 + i * 16 + (lane >> 4) * 4 + r;
          obuf[(size_t)((((b << 10) | n) << 2) | t) * 512 + h * 64 + et * 16 + rsel] = f2bf(acc[i][et][r]);
        }
  }
}

// ---------------------------------------------------------------------------
extern "C" void kernel_launch(void* const* d_in, const int* in_sizes, int n_in,
                              void* d_out, int out_size, void* d_ws, size_t ws_size,
                              hipStream_t stream) {
  char* ws = (char*)d_ws;
  unsigned short* X2   = (unsigned short*)(ws + 0);            // 32 MB [m'][1024]
  unsigned short* Wqk3 = (unsigned short*)(ws + 33554432ull);  // 3 MB
  unsigned short* Wvb  = (unsigned short*)(ws + 36700160ull);  // 0.5 MB
  unsigned short* Wpb  = (unsigned short*)(ws + 37224448ull);  // 0.5 MB
  float*          scl  = (float*)(ws + 37748736ull);           // 8 KB
  float*          sft  = (float*)(ws + 37756928ull);           // 8 KB
  unsigned short* qsb  = (unsigned short*)(ws + 41943040ull);  // 16 MB [m'][512]
  unsigned short* ktr  = (unsigned short*)(ws + 58720256ull);  // 16 MB [t,b,c,n]
  unsigned short* vtr  = (unsigned short*)(ws + 75497472ull);  // 16 MB [t,b,c,n]
  unsigned short* kvt  = (unsigned short*)(ws + 92274688ull);  // 1 MB
  unsigned short* ob   = (unsigned short*)(ws + 93323264ull);  // 16 MB [m'][512]

  PrepArgs pa;
  pa.x  = (const float*)d_in[0];
  pa.qw = (const float*)d_in[2];
  pa.kw = (const float*)d_in[8];
  pa.vw = (const float*)d_in[14];
  pa.pw = (const float*)d_in[20];
  pa.X2 = X2; pa.Wqk3 = Wqk3; pa.Wvb = Wvb; pa.Wpb = Wpb;
  pa.scl = scl; pa.sft = sft;
  pa.bp.p[0]=(const float*)d_in[3];  pa.bp.p[1]=(const float*)d_in[4];  pa.bp.p[2]=(const float*)d_in[5];  pa.bp.p[3]=(const float*)d_in[6];  pa.bp.p[4]=(const float*)d_in[7];
  pa.bp.p[5]=(const float*)d_in[9];  pa.bp.p[6]=(const float*)d_in[10]; pa.bp.p[7]=(const float*)d_in[11]; pa.bp.p[8]=(const float*)d_in[12]; pa.bp.p[9]=(const float*)d_in[13];
  pa.bp.p[10]=(const float*)d_in[15];pa.bp.p[11]=(const float*)d_in[16];pa.bp.p[12]=(const float*)d_in[17];pa.bp.p[13]=(const float*)d_in[18];pa.bp.p[14]=(const float*)d_in[19];
  pa.bp.p[15]=(const float*)d_in[21];pa.bp.p[16]=(const float*)d_in[22];pa.bp.p[17]=(const float*)d_in[23];pa.bp.p[18]=(const float*)d_in[24];pa.bp.p[19]=(const float*)d_in[25];
  prep_all<<<dim3(9224), 256, 0, stream>>>(pa);

  Job2 jqk{X2, 1024, Wqk3, 1536, 1536, 512, 2, scl, sft, nullptr, qsb, ktr};
  Job2 jv {X2, 1024, Wvb,  512,  512,  512, 4, scl + 1024, sft + 1024, nullptr, nullptr, vtr};
  gemm_fused<<<dim3(512), 512, 0, stream>>>(jqk, jv);

  kv_gemm<<<dim3(128), 256, 0, stream>>>(ktr, vtr, kvt);
  av_gemm<<<dim3(256), 256, 0, stream>>>(qsb, kvt, ob);

  Job2 jp{ob, 512, Wpb, 512, 512, 512, 3, scl + 1536, sft + 1536, (float*)d_out, nullptr, nullptr};
  gemm128<<<dim3(256), 512, 0, stream>>>(jp);
}